// Round 4
// baseline (610.813 us; speedup 1.0000x reference)
//
#include <hip/hip_runtime.h>
#include <hip/hip_bf16.h>
#include <cstdint>
#include <cstddef>

// Shapes: B=2, S=512, C=25, H=768, 2H=1536, 3H=2304, 4H=3072
#define BB 2
#define SS 512
#define CC 25
#define HH 768
#define H2 1536
#define H3 2304
#define H4 3072

typedef __attribute__((ext_vector_type(8))) short bf16x8;
typedef __attribute__((ext_vector_type(4))) float f32x4;

#define DEVINL static __device__ __forceinline__

DEVINL unsigned short f2bf(float f) {
  union { float f; unsigned u; } v; v.f = f;
  unsigned r = v.u + 0x7FFF + ((v.u >> 16) & 1);  // RNE
  return (unsigned short)(r >> 16);
}
DEVINL float bf2f(unsigned short b) {
  union { unsigned u; float f; } v; v.u = ((unsigned)b) << 16; return v.f;
}

DEVINL void async16(const void* g, void* l) {
  __builtin_amdgcn_global_load_lds(
      (const __attribute__((address_space(1))) void*)g,
      (__attribute__((address_space(3))) void*)l, 16, 0, 0);
}

// ---------------- small kernels ----------------

__global__ void k_f32_to_bf16(const float* __restrict__ in,
                              unsigned short* __restrict__ out, int n) {
  int i = blockIdx.x * 256 + threadIdx.x;
  if (i < n) out[i] = f2bf(in[i]);
}

__global__ void k_zero_f32(float* __restrict__ p, int n) {
  int i = blockIdx.x * 256 + threadIdx.x;
  if (i < n) p[i] = 0.f;
}

__global__ void k_transpose_bf16(const float* __restrict__ in,
                                 unsigned short* __restrict__ out,
                                 int R, int C) {
  __shared__ float tile[32][33];
  int c0 = blockIdx.x * 32, r0 = blockIdx.y * 32;
  int tx = threadIdx.x, ty = threadIdx.y;  // block (32,8)
#pragma unroll
  for (int i = 0; i < 4; i++)
    tile[ty + i * 8][tx] = in[(size_t)(r0 + ty + i * 8) * C + c0 + tx];
  __syncthreads();
#pragma unroll
  for (int i = 0; i < 4; i++)
    out[(size_t)(c0 + ty + i * 8) * R + r0 + tx] = f2bf(tile[tx][ty + i * 8]);
}

__global__ void k_lp_finish(const float* __restrict__ lp_f32,
                            const float* __restrict__ bl,
                            unsigned short* __restrict__ lpbf, int n) {
  int i = blockIdx.x * 256 + threadIdx.x;
  if (i < n) lpbf[i] = f2bf(lp_f32[i] + bl[i % H2]);
}

// X[bc][s][h] = tb[b][s][h] * lb[b][c][h]
__global__ void k_make_x(const unsigned short* __restrict__ tp,
                         const unsigned short* __restrict__ lp,
                         unsigned short* __restrict__ X) {
  int idx = blockIdx.x * 256 + threadIdx.x;
  if (idx >= CC * BB * SS * (HH / 8)) return;
  int hc = idx % (HH / 8);
  int rest = idx / (HH / 8);
  int s = rest % SS;
  int bc = rest / SS;
  int b = bc / CC;
  const bf16x8 tv = *(const bf16x8*)&tp[(size_t)(b * SS + s) * H2 + HH + hc * 8];
  const bf16x8 lv = *(const bf16x8*)&lp[(size_t)bc * H2 + HH + hc * 8];
  bf16x8 o;
#pragma unroll
  for (int j = 0; j < 8; j++) {
    float f = bf2f((unsigned short)tv[j]) * bf2f((unsigned short)lv[j]);
    o[j] = (short)f2bf(f);
  }
  *(bf16x8*)&X[(size_t)(bc * SS + s) * HH + hc * 8] = o;
}

__global__ void k_init_out(float* __restrict__ out, const float* __restrict__ b2, int n) {
  int i = blockIdx.x * 256 + threadIdx.x;
  if (i < n) out[i] = b2[i % 3];
}

// ---------------- legacy 128x128 split-K GEMM (for tiny-M label GEMMs) ------
__global__ __launch_bounds__(256, 3) void gemm_main3(
    const unsigned short* __restrict__ A, int lda,
    const unsigned short* __restrict__ Bt, int ldb,
    int M, int Klen, float* __restrict__ Cf, int ldc) {
  __shared__ __align__(16) unsigned short As[8 * 128 * 8];
  __shared__ __align__(16) unsigned short Bs[8 * 128 * 8];

  const int tid = threadIdx.x;
  const int lane = tid & 63;
  const int wave = tid >> 6;
  const int q = lane >> 4;
  const int li = lane & 15;
  const int wm = (wave >> 1) * 64;
  const int wn = (wave & 1) * 64;

  const int n0 = blockIdx.x * 128;
  const int m0 = blockIdx.y * 128;
  const int kofs = blockIdx.z * Klen;

  const int r = tid & 127;
  const int kcb = (tid >> 7) * 8;
  const int ra = min(m0 + r, M - 1);
  const unsigned short* gA = A + (size_t)ra * lda + kcb + kofs;
  const unsigned short* gB = Bt + (size_t)(n0 + r) * ldb + kcb + kofs;
  char* lA = (char*)As + tid * 16;
  char* lB = (char*)Bs + tid * 16;

  f32x4 acc[4][4];
#pragma unroll
  for (int i = 0; i < 4; i++)
#pragma unroll
    for (int j = 0; j < 4; j++) acc[i][j] = (f32x4){0.f, 0.f, 0.f, 0.f};

  const unsigned short* lAf = &As[(q * 128 + wm + li) * 8];
  const unsigned short* lBf = &Bs[(q * 128 + wn + li) * 8];

#pragma unroll
  for (int t = 0; t < 4; t++) {
    async16(gA + t * 16, lA + t * 4096);
    async16(gB + t * 16, lB + t * 4096);
  }

  for (int k0 = 0; k0 < Klen; k0 += 64) {
    __syncthreads();
    bf16x8 af[2][4], bb[2][4];
#pragma unroll
    for (int ck = 0; ck < 2; ck++)
#pragma unroll
      for (int mi = 0; mi < 4; mi++) {
        af[ck][mi] = *(const bf16x8*)(lAf + ck * 4096 + mi * 128);
        bb[ck][mi] = *(const bf16x8*)(lBf + ck * 4096 + mi * 128);
      }
    __syncthreads();
    if (k0 + 64 < Klen) {
#pragma unroll
      for (int t = 0; t < 4; t++) {
        async16(gA + k0 + 64 + t * 16, lA + t * 4096);
        async16(gB + k0 + 64 + t * 16, lB + t * 4096);
      }
    }
#pragma unroll
    for (int ck = 0; ck < 2; ck++)
#pragma unroll
      for (int mi = 0; mi < 4; mi++)
#pragma unroll
        for (int ni = 0; ni < 4; ni++)
          acc[mi][ni] = __builtin_amdgcn_mfma_f32_16x16x32_bf16(
              af[ck][mi], bb[ck][ni], acc[mi][ni], 0, 0, 0);
  }

#pragma unroll
  for (int mi = 0; mi < 4; mi++)
#pragma unroll
    for (int rr = 0; rr < 4; rr++) {
      int row = m0 + wm + mi * 16 + q * 4 + rr;
      if (row < M) {
#pragma unroll
        for (int ni = 0; ni < 4; ni++) {
          int col = n0 + wn + ni * 16 + li;
          atomicAdd(&Cf[(size_t)row * ldc + col], acc[mi][ni][rr]);
        }
      }
    }
}

// ---------------- 256x128 tile, BK=32, double-buffered, 1 barrier/iter ------
// Wave grid 2x2: wave-tile 128m x 64n. acc[8][4] f32x4.
// LDS: As[st] = [kcchunk(4)][row(256)][8]; Bs[st] = [kcchunk(4)][row(128)][8]
// MODE 0: Cbf = bf16(acc + bias[col]);  MODE 1: Cf = acc;  MODE 2: scorer.
template <int MODE>
__global__ __launch_bounds__(256, 2) void gemm256(
    const unsigned short* __restrict__ A, int lda,
    const unsigned short* __restrict__ Bt, int ldb,
    int M, int K,
    unsigned short* __restrict__ Cbf, float* __restrict__ Cf, int ldc,
    const float* __restrict__ bias,
    const float* __restrict__ base, const float* __restrict__ al,
    const float* __restrict__ b1, const float* __restrict__ W2,
    float* __restrict__ out) {
  __shared__ __align__(16) unsigned short As[2][8192];
  __shared__ __align__(16) unsigned short Bs[2][4096];

  const int tid = threadIdx.x;
  const int lane = tid & 63;
  const int wave = tid >> 6;
  const int q = lane >> 4;
  const int li = lane & 15;
  const int wm = (wave >> 1) * 128;   // 0 / 128
  const int wn = (wave & 1) * 64;     // 0 / 64

  const int n0 = blockIdx.x * 128;
  const int m0 = blockIdx.y * 256;

  // staging addresses
  const int arow = min(m0 + tid, M - 1);
  const unsigned short* gA = A + (size_t)arow * lda;           // + k0 + j*8
  const int brow = tid & 127;
  const int bkc = tid >> 7;                                    // 0/1
  const unsigned short* gB = Bt + (size_t)(n0 + brow) * ldb;   // + k0 + (j*2+bkc)*8

  f32x4 acc[8][4];
#pragma unroll
  for (int i = 0; i < 8; i++)
#pragma unroll
    for (int j = 0; j < 4; j++) acc[i][j] = (f32x4){0.f, 0.f, 0.f, 0.f};

  const unsigned short* lAf0 = &As[0][q * 2048 + (wm + li) * 8];
  const unsigned short* lAf1 = &As[1][q * 2048 + (wm + li) * 8];
  const unsigned short* lBf0 = &Bs[0][q * 1024 + (wn + li) * 8];
  const unsigned short* lBf1 = &Bs[1][q * 1024 + (wn + li) * 8];

  auto stage = [&](int k0, int st) {
    unsigned short* a = &As[st][tid * 8];                 // [kcchunk j][row tid][8]
    unsigned short* b = &Bs[st][bkc * 1024 + brow * 8];   // [kcchunk j*2+bkc][row brow][8]
#pragma unroll
    for (int j = 0; j < 4; j++) async16(gA + k0 + j * 8, a + j * 2048);
#pragma unroll
    for (int j = 0; j < 2; j++) async16(gB + k0 + (j * 2 + bkc) * 8, b + j * 2048);
  };

  stage(0, 0);
  const int NI = K / 32;
  for (int i = 0; i < NI; i++) {
    __syncthreads();  // stage(i) landed; prev-iter LDS reads done
    if (i + 1 < NI) stage((i + 1) * 32, (i + 1) & 1);

    const unsigned short* lA = (i & 1) ? lAf1 : lAf0;
    const unsigned short* lB = (i & 1) ? lBf1 : lBf0;
    bf16x8 af[8], bb[4];
#pragma unroll
    for (int ni = 0; ni < 4; ni++) bb[ni] = *(const bf16x8*)(lB + ni * 128);
#pragma unroll
    for (int mi = 0; mi < 8; mi++) af[mi] = *(const bf16x8*)(lA + mi * 128);
#pragma unroll
    for (int mi = 0; mi < 8; mi++)
#pragma unroll
      for (int ni = 0; ni < 4; ni++)
        acc[mi][ni] = __builtin_amdgcn_mfma_f32_16x16x32_bf16(
            af[mi], bb[ni], acc[mi][ni], 0, 0, 0);
  }

  // ---------------- epilogues ----------------
  if (MODE == 0 || MODE == 1) {
#pragma unroll
    for (int mi = 0; mi < 8; mi++)
#pragma unroll
      for (int rr = 0; rr < 4; rr++) {
        int row = m0 + wm + mi * 16 + q * 4 + rr;
        if (row < M) {
#pragma unroll
          for (int ni = 0; ni < 4; ni++) {
            int col = n0 + wn + ni * 16 + li;
            if (MODE == 0)
              Cbf[(size_t)row * ldc + col] = f2bf(acc[mi][ni][rr] + bias[col]);
            else
              Cf[(size_t)row * ldc + col] = acc[mi][ni][rr];
          }
        }
      }
  } else {
    const int bc = m0 >> 9;  // 256-row tile lies within one bc (512 rows/bc)
    const int b = bc / CC, c = bc % CC;
    float alb[4], w20[4], w21[4], w22[4];
    int fcol[4];
#pragma unroll
    for (int ni = 0; ni < 4; ni++) {
      int f = n0 + wn + ni * 16 + li;
      fcol[ni] = f;
      alb[ni] = al[(size_t)bc * H4 + f] + b1[f];
      w20[ni] = W2[f * 3 + 0];
      w21[ni] = W2[f * 3 + 1];
      w22[ni] = W2[f * 3 + 2];
    }
#pragma unroll
    for (int mi = 0; mi < 8; mi++)
#pragma unroll
      for (int rr = 0; rr < 4; rr++) {
        int g = m0 + wm + mi * 16 + q * 4 + rr;
        int s = g & 511;
        const float* brow_p = base + (size_t)(b * SS + s) * H4;
        float s0 = 0.f, s1 = 0.f, s2 = 0.f;
#pragma unroll
        for (int ni = 0; ni < 4; ni++) {
          float v = acc[mi][ni][rr] + brow_p[fcol[ni]] + alb[ni];
          v = fmaxf(v, 0.f);
          s0 = fmaf(v, w20[ni], s0);
          s1 = fmaf(v, w21[ni], s1);
          s2 = fmaf(v, w22[ni], s2);
        }
#pragma unroll
        for (int off = 1; off < 16; off <<= 1) {
          s0 += __shfl_xor(s0, off);
          s1 += __shfl_xor(s1, off);
          s2 += __shfl_xor(s2, off);
        }
        if (li == 0) {
          float* op = out + (size_t)((b * SS + s) * CC + c) * 3;
          atomicAdd(op + 0, s0);
          atomicAdd(op + 1, s1);
          atomicAdd(op + 2, s2);
        }
      }
  }
}

// ---------------- host launch ----------------

extern "C" void kernel_launch(void* const* d_in, const int* in_sizes, int n_in,
                              void* d_out, int out_size, void* d_ws, size_t ws_size,
                              hipStream_t stream) {
  (void)in_sizes; (void)n_in; (void)ws_size;
  const float* token = (const float*)d_in[0];
  const float* label = (const float*)d_in[1];
  const float* Wt    = (const float*)d_in[2];
  const float* bt    = (const float*)d_in[3];
  const float* Wl    = (const float*)d_in[4];
  const float* bl    = (const float*)d_in[5];
  const float* W1    = (const float*)d_in[6];
  const float* b1    = (const float*)d_in[7];
  const float* W2    = (const float*)d_in[8];
  const float* b2    = (const float*)d_in[9];
  float* out = (float*)d_out;

  char* p = (char*)d_ws;
  auto alloc = [&](size_t bytes) {
    char* r = p;
    p += (bytes + 255) & ~(size_t)255;
    return r;
  };
  unsigned short* Tbf  = (unsigned short*)alloc((size_t)BB * SS * HH * 2);
  unsigned short* Lbf  = (unsigned short*)alloc((size_t)BB * CC * HH * 2);
  unsigned short* WtT  = (unsigned short*)alloc((size_t)H2 * HH * 2);
  unsigned short* WlT  = (unsigned short*)alloc((size_t)H2 * HH * 2);
  unsigned short* W1T  = (unsigned short*)alloc((size_t)H4 * H3 * 2);
  unsigned short* tpbf = (unsigned short*)alloc((size_t)BB * SS * H2 * 2);
  unsigned short* lpbf = (unsigned short*)alloc((size_t)BB * CC * H2 * 2);
  unsigned short* Xall = (unsigned short*)alloc((size_t)BB * CC * SS * HH * 2);
  float* base   = (float*)alloc((size_t)BB * SS * H4 * 4);
  float* al     = (float*)alloc((size_t)BB * CC * H4 * 4);
  float* lp_f32 = (float*)alloc((size_t)BB * CC * H2 * 4);

  const int nT = BB * SS * HH;
  const int nL = BB * CC * HH;
  const int nLP = BB * CC * H2;
  const int nAL = BB * CC * H4;

  k_f32_to_bf16<<<(nT + 255) / 256, 256, 0, stream>>>(token, Tbf, nT);
  k_f32_to_bf16<<<(nL + 255) / 256, 256, 0, stream>>>(label, Lbf, nL);
  k_transpose_bf16<<<dim3(H2 / 32, HH / 32), dim3(32, 8), 0, stream>>>(Wt, WtT, HH, H2);
  k_transpose_bf16<<<dim3(H2 / 32, HH / 32), dim3(32, 8), 0, stream>>>(Wl, WlT, HH, H2);
  k_transpose_bf16<<<dim3(H4 / 32, H3 / 32), dim3(32, 8), 0, stream>>>(W1, W1T, H3, H4);

  k_zero_f32<<<(nAL + nLP + 255) / 256, 256, 0, stream>>>(al, nAL + nLP);

  // G1: tp = T @ Wt + bt  (M=1024, N=1536, K=768) -> bf16
  gemm256<0><<<dim3(H2 / 128, (BB * SS) / 256), 256, 0, stream>>>(
      Tbf, HH, WtT, HH, BB * SS, HH, tpbf, nullptr, H2, bt,
      nullptr, nullptr, nullptr, nullptr, nullptr);
  // G2: lp_f32 += L @ Wl  (M=50, split-K 4)
  gemm_main3<<<dim3(H2 / 128, 1, 4), 256, 0, stream>>>(
      Lbf, HH, WlT, HH, BB * CC, HH / 4, lp_f32, H2);
  k_lp_finish<<<(nLP + 255) / 256, 256, 0, stream>>>(lp_f32, bl, lpbf, nLP);
  // G4: al += la @ W1l  (M=50, split-K 4)
  gemm_main3<<<dim3(H4 / 128, 1, 4), 256, 0, stream>>>(
      lpbf, H2, W1T + HH, H3, BB * CC, HH / 4, al, H4);

  // X = tb .* lb
  const int nX = BB * CC * SS * (HH / 8);
  k_make_x<<<(nX + 255) / 256, 256, 0, stream>>>(tpbf, lpbf, Xall);

  // G3: base = ta @ W1t  (M=1024, N=3072, K=768) -> fp32
  gemm256<1><<<dim3(H4 / 128, (BB * SS) / 256), 256, 0, stream>>>(
      tpbf, H2, W1T, H3, BB * SS, HH, nullptr, base, H4, nullptr,
      nullptr, nullptr, nullptr, nullptr, nullptr);

  k_init_out<<<(out_size + 255) / 256, 256, 0, stream>>>(out, b2, out_size);

  // G5: scorer, 100 m-tiles x 24 n-tiles, n fastest
  gemm256<2><<<dim3(H4 / 128, (BB * CC * SS) / 256), 256, 0, stream>>>(
      Xall, HH, W1T + H2, H3, BB * CC * SS, HH, nullptr, nullptr, 0,
      nullptr, base, al, b1, W2, out);
}

// Round 5
// 308.134 us; speedup vs baseline: 1.9823x; 1.9823x over previous
//
#include <hip/hip_runtime.h>
#include <hip/hip_bf16.h>
#include <cstdint>
#include <cstddef>

// Shapes: B=2, S=512, C=25, H=768, 2H=1536, 3H=2304, 4H=3072
#define BB 2
#define SS 512
#define CC 25
#define HH 768
#define H2 1536
#define H3 2304
#define H4 3072
// chunked layout: [kc][row][8] bf16, kc = k/8
#define XC_STRIDE ((size_t)96 * 512 * 8)   // per-bc X slab, 96 chunks x 512 rows

typedef __attribute__((ext_vector_type(8))) short bf16x8;
typedef __attribute__((ext_vector_type(4))) float f32x4;

#define DEVINL static __device__ __forceinline__

DEVINL unsigned short f2bf(float f) {
  union { float f; unsigned u; } v; v.f = f;
  unsigned r = v.u + 0x7FFF + ((v.u >> 16) & 1);  // RNE
  return (unsigned short)(r >> 16);
}
DEVINL float bf2f(unsigned short b) {
  union { unsigned u; float f; } v; v.u = ((unsigned)b) << 16; return v.f;
}

DEVINL void async16(const void* g, void* l) {
  __builtin_amdgcn_global_load_lds(
      (const __attribute__((address_space(1))) void*)g,
      (__attribute__((address_space(3))) void*)l, 16, 0, 0);
}

// ---------------- layout/cast kernels ----------------

// f32 row-major [R][K] -> bf16 chunked [K/8][RP][8]; rows clamped (dup last).
// grid (K/32, RP/32), block (32,4)
__global__ void k_cast_chunk(const float* __restrict__ in,
                             unsigned short* __restrict__ out,
                             int R, int K, int RP) {
  __shared__ float tile[32][33];
  int k0 = blockIdx.x * 32, r0 = blockIdx.y * 32;
  int tx = threadIdx.x, ty = threadIdx.y;
#pragma unroll
  for (int i = 0; i < 8; i++) {
    int r = r0 + ty + i * 4;
    int rr = min(r, R - 1);
    tile[ty + i * 4][tx] = in[(size_t)rr * K + k0 + tx];
  }
  __syncthreads();
  // thread (tx=row-local, ty=kc-local 0..3)
  bf16x8 o;
#pragma unroll
  for (int j = 0; j < 8; j++) o[j] = (short)f2bf(tile[tx][ty * 8 + j]);
  *(bf16x8*)&out[((size_t)((k0 >> 3) + ty) * RP + r0 + tx) * 8] = o;
}

// weight f32 [Hd][N] -> bf16 chunked [Hd/8][N][8].  grid (N/64, Hd/32), block 256
__global__ void k_chunkW(const float* __restrict__ in,
                         unsigned short* __restrict__ out, int N, int Hd) {
  int tid = threadIdx.x;
  int f = blockIdx.x * 64 + (tid & 63);
  int hc = blockIdx.y * 4 + (tid >> 6);
  bf16x8 o;
#pragma unroll
  for (int j = 0; j < 8; j++)
    o[j] = (short)f2bf(in[(size_t)(hc * 8 + j) * N + f]);
  *(bf16x8*)&out[((size_t)hc * N + f) * 8] = o;
}

__global__ void k_zero_f32(float* __restrict__ p, int n) {
  int i = blockIdx.x * 256 + threadIdx.x;
  if (i < n) p[i] = 0.f;
}

// lp_f32 [50][1536] + bl -> LP chunked [192][64][8]
__global__ void k_lp_finish(const float* __restrict__ lp_f32,
                            const float* __restrict__ bl,
                            unsigned short* __restrict__ lpC, int n) {
  int i = blockIdx.x * 256 + threadIdx.x;
  if (i >= n) return;
  int col = i % H2, row = i / H2;
  float v = lp_f32[i] + bl[col];
  lpC[((size_t)(col >> 3) * 64 + row) * 8 + (col & 7)] = f2bf(v);
}

// X chunked: XC[bc][hc][s][8] = tb_chunk(96+hc)[b*512+s] * lb_chunk(96+hc)[bc]
// grid (192, 50), block 256
__global__ void k_make_x(const unsigned short* __restrict__ TP,
                         const unsigned short* __restrict__ LP,
                         unsigned short* __restrict__ XC) {
  int hc = blockIdx.x >> 1;
  int s = (blockIdx.x & 1) * 256 + threadIdx.x;
  int bc = blockIdx.y;
  int b = bc / CC;
  bf16x8 tv = *(const bf16x8*)&TP[((size_t)(96 + hc) * 1024 + b * 512 + s) * 8];
  bf16x8 lv = *(const bf16x8*)&LP[((size_t)(96 + hc) * 64 + bc) * 8];
  bf16x8 o;
#pragma unroll
  for (int j = 0; j < 8; j++)
    o[j] = (short)f2bf(bf2f((unsigned short)tv[j]) * bf2f((unsigned short)lv[j]));
  *(bf16x8*)&XC[(size_t)bc * XC_STRIDE + ((size_t)hc * 512 + s) * 8] = o;
}

__global__ void k_init_out(float* __restrict__ out, const float* __restrict__ b2, int n) {
  int i = blockIdx.x * 256 + threadIdx.x;
  if (i < n) out[i] = b2[i % 3];
}

// ---------------- 128x128 GEMM, BK=64, chunked operands ----------------
// A chunked [kc][NRA][8] (rows clamp to MA), B chunked [kc][NRB][8].
// MODE 0: bf16 chunked out [(col/8)*ldc + row][col%8] = acc + bias[col]
// MODE 1: f32 row-major Cf[row*ldc+col] = acc
// MODE 2: scorer epilogue (A = XC slab per bc, M local 512)
// MODE 3: atomicAdd f32 row-major (split-K over blockIdx.z)
template <int MODE>
__global__ __launch_bounds__(256, 4) void gemmC(
    const unsigned short* __restrict__ A, int NRA, int MA,
    const unsigned short* __restrict__ Bt, int NRB,
    int Klen,
    unsigned short* __restrict__ Cbf, float* __restrict__ Cf, int ldc,
    const float* __restrict__ bias,
    const float* __restrict__ base, const float* __restrict__ al,
    const float* __restrict__ b1, const float* __restrict__ W2,
    float* __restrict__ out) {
  __shared__ __align__(16) unsigned short As[8 * 128 * 8];  // [kc(8)][row(128)][8]
  __shared__ __align__(16) unsigned short Bs[8 * 128 * 8];

  const int tid = threadIdx.x;
  const int lane = tid & 63;
  const int wave = tid >> 6;
  const int q = lane >> 4;
  const int li = lane & 15;
  const int wm = (wave >> 1) * 64;
  const int wn = (wave & 1) * 64;

  const int n0 = blockIdx.x * 128;
  int m0, bc = 0;
  const unsigned short* Ab = A;
  if (MODE == 2) {
    bc = blockIdx.y >> 2;
    m0 = (blockIdx.y & 3) * 128;
    Ab = A + (size_t)bc * XC_STRIDE;
  } else {
    m0 = blockIdx.y * 128;
  }
  const int kc_base = (MODE == 3) ? blockIdx.z * (Klen >> 3) : 0;

  f32x4 acc[4][4];
#pragma unroll
  for (int i = 0; i < 4; i++)
#pragma unroll
    for (int j = 0; j < 4; j++) acc[i][j] = (f32x4){0.f, 0.f, 0.f, 0.f};

  // staging: slot = j*256+tid -> kc = slot>>7, r = slot&127; LDS offset slot*16B
  int sr[4], skc[4], sra[4];
#pragma unroll
  for (int j = 0; j < 4; j++) {
    int slot = j * 256 + tid;
    skc[j] = slot >> 7;
    sr[j] = slot & 127;
    sra[j] = min(m0 + sr[j], MA - 1);
  }

  auto stage = [&](int kciter) {  // kciter = chunk index of BK64 step start
#pragma unroll
    for (int j = 0; j < 4; j++) {
      int slot = j * 256 + tid;
      async16(Ab + ((size_t)(kciter + skc[j]) * NRA + sra[j]) * 8,
              (char*)As + slot * 16);
      async16(Bt + ((size_t)(kciter + skc[j]) * NRB + n0 + sr[j]) * 8,
              (char*)Bs + slot * 16);
    }
  };

  stage(kc_base);
  const int NI = Klen / 64;
  for (int it = 0; it < NI; it++) {
    __syncthreads();  // stage landed
#pragma unroll
    for (int ks = 0; ks < 2; ks++) {
      bf16x8 af[4], bb[4];
#pragma unroll
      for (int mi = 0; mi < 4; mi++)
        af[mi] = *(const bf16x8*)&As[((ks * 4 + q) * 128 + wm + mi * 16 + li) * 8];
#pragma unroll
      for (int ni = 0; ni < 4; ni++)
        bb[ni] = *(const bf16x8*)&Bs[((ks * 4 + q) * 128 + wn + ni * 16 + li) * 8];
#pragma unroll
      for (int mi = 0; mi < 4; mi++)
#pragma unroll
        for (int ni = 0; ni < 4; ni++)
          acc[mi][ni] = __builtin_amdgcn_mfma_f32_16x16x32_bf16(
              af[mi], bb[ni], acc[mi][ni], 0, 0, 0);
    }
    __syncthreads();  // all reads done
    if (it + 1 < NI) stage(kc_base + (it + 1) * 8);
  }

  // ---------------- epilogues ----------------
  if (MODE == 0) {
#pragma unroll
    for (int mi = 0; mi < 4; mi++)
#pragma unroll
      for (int rr = 0; rr < 4; rr++) {
        int row = m0 + wm + mi * 16 + q * 4 + rr;
#pragma unroll
        for (int ni = 0; ni < 4; ni++) {
          int col = n0 + wn + ni * 16 + li;
          Cbf[((size_t)(col >> 3) * ldc + row) * 8 + (col & 7)] =
              f2bf(acc[mi][ni][rr] + bias[col]);
        }
      }
  } else if (MODE == 1) {
#pragma unroll
    for (int mi = 0; mi < 4; mi++)
#pragma unroll
      for (int rr = 0; rr < 4; rr++) {
        int row = m0 + wm + mi * 16 + q * 4 + rr;
#pragma unroll
        for (int ni = 0; ni < 4; ni++) {
          int col = n0 + wn + ni * 16 + li;
          Cf[(size_t)row * ldc + col] = acc[mi][ni][rr];
        }
      }
  } else if (MODE == 3) {
#pragma unroll
    for (int mi = 0; mi < 4; mi++)
#pragma unroll
      for (int rr = 0; rr < 4; rr++) {
        int row = m0 + wm + mi * 16 + q * 4 + rr;
        if (row < MA) {
#pragma unroll
          for (int ni = 0; ni < 4; ni++) {
            int col = n0 + wn + ni * 16 + li;
            atomicAdd(&Cf[(size_t)row * ldc + col], acc[mi][ni][rr]);
          }
        }
      }
  } else {
    // MODE 2: scorer. E = acc + base + al + b1; relu; out += E @ W2 (MFMA)
    const int b = bc / CC, c = bc % CC;
    int fcol[4];
    float alb[4];
#pragma unroll
    for (int ni = 0; ni < 4; ni++) {
      int f = n0 + wn + ni * 16 + li;
      fcol[ni] = f;
      alb[ni] = al[(size_t)bc * H4 + f] + b1[f];
    }
    // W2 B-fragments: lane holds W2[k=q*8+j (f-local)][n=li], li<3 real
    bf16x8 w2f[2];
#pragma unroll
    for (int ks = 0; ks < 2; ks++)
#pragma unroll
      for (int jj = 0; jj < 8; jj++) {
        int f = n0 + wn + ks * 32 + q * 8 + jj;
        float v = (li < 3) ? W2[(size_t)f * 3 + li] : 0.f;
        w2f[ks][jj] = (short)f2bf(v);
      }
    // per-wave LDS scratch: 16 rows x (64+8) bf16, stride 72
    unsigned short* Ew = (unsigned short*)((char*)As + wave * 2304);

#pragma unroll
    for (int mi = 0; mi < 4; mi++) {
      float bs[4][4];
#pragma unroll
      for (int rr = 0; rr < 4; rr++) {
        int s_l = m0 + wm + mi * 16 + q * 4 + rr;
        const float* bp = base + (size_t)(b * SS + s_l) * H4;
#pragma unroll
        for (int ni = 0; ni < 4; ni++) bs[ni][rr] = bp[fcol[ni]];
      }
#pragma unroll
      for (int rr = 0; rr < 4; rr++)
#pragma unroll
        for (int ni = 0; ni < 4; ni++) {
          float v = acc[mi][ni][rr] + bs[ni][rr] + alb[ni];
          v = fmaxf(v, 0.f);
          Ew[(q * 4 + rr) * 72 + ni * 16 + li] = f2bf(v);
        }
      f32x4 oc = (f32x4){0.f, 0.f, 0.f, 0.f};
#pragma unroll
      for (int ks = 0; ks < 2; ks++) {
        bf16x8 ef = *(const bf16x8*)&Ew[li * 72 + ks * 32 + q * 8];
        oc = __builtin_amdgcn_mfma_f32_16x16x32_bf16(ef, w2f[ks], oc, 0, 0, 0);
      }
#pragma unroll
      for (int rr = 0; rr < 4; rr++) {
        int s_l = m0 + wm + mi * 16 + q * 4 + rr;
        if (li < 3)
          atomicAdd(&out[((size_t)(b * SS + s_l) * CC + c) * 3 + li], oc[rr]);
      }
    }
  }
}

// ---------------- host launch ----------------

extern "C" void kernel_launch(void* const* d_in, const int* in_sizes, int n_in,
                              void* d_out, int out_size, void* d_ws, size_t ws_size,
                              hipStream_t stream) {
  (void)in_sizes; (void)n_in; (void)ws_size;
  const float* token = (const float*)d_in[0];
  const float* label = (const float*)d_in[1];
  const float* Wt    = (const float*)d_in[2];
  const float* bt    = (const float*)d_in[3];
  const float* Wl    = (const float*)d_in[4];
  const float* bl    = (const float*)d_in[5];
  const float* W1    = (const float*)d_in[6];
  const float* b1    = (const float*)d_in[7];
  const float* W2    = (const float*)d_in[8];
  const float* b2    = (const float*)d_in[9];
  float* out = (float*)d_out;

  char* p = (char*)d_ws;
  auto alloc = [&](size_t bytes) {
    char* r = p;
    p += (bytes + 255) & ~(size_t)255;
    return r;
  };
  unsigned short* TC  = (unsigned short*)alloc((size_t)96 * 1024 * 8 * 2);
  unsigned short* LC  = (unsigned short*)alloc((size_t)96 * 64 * 8 * 2);
  unsigned short* WtC = (unsigned short*)alloc((size_t)96 * 1536 * 8 * 2);
  unsigned short* WlC = (unsigned short*)alloc((size_t)96 * 1536 * 8 * 2);
  unsigned short* W1C = (unsigned short*)alloc((size_t)288 * 3072 * 8 * 2);
  unsigned short* TP  = (unsigned short*)alloc((size_t)192 * 1024 * 8 * 2);
  unsigned short* LP  = (unsigned short*)alloc((size_t)192 * 64 * 8 * 2);
  unsigned short* XC  = (unsigned short*)alloc((size_t)CC * BB * XC_STRIDE * 2);
  float* base   = (float*)alloc((size_t)BB * SS * H4 * 4);
  float* al     = (float*)alloc((size_t)BB * CC * H4 * 4);
  float* lp_f32 = (float*)alloc((size_t)BB * CC * H2 * 4);

  const int nLP = BB * CC * H2;   // 76800
  const int nAL = BB * CC * H4;   // 153600

  // layout prep
  k_cast_chunk<<<dim3(24, 32), dim3(32, 4), 0, stream>>>(token, TC, 1024, HH, 1024);
  k_cast_chunk<<<dim3(24, 2), dim3(32, 4), 0, stream>>>(label, LC, 50, HH, 64);
  k_chunkW<<<dim3(24, 24), 256, 0, stream>>>(Wt, WtC, H2, HH);
  k_chunkW<<<dim3(24, 24), 256, 0, stream>>>(Wl, WlC, H2, HH);
  k_chunkW<<<dim3(48, 72), 256, 0, stream>>>(W1, W1C, H4, H3);
  k_zero_f32<<<(nAL + nLP + 255) / 256, 256, 0, stream>>>(al, nAL + nLP);

  // G1: tp = T @ Wt + bt -> TP chunked (M=1024, N=1536, K=768)
  gemmC<0><<<dim3(12, 8), 256, 0, stream>>>(
      TC, 1024, 1024, WtC, H2, HH, TP, nullptr, 1024, bt,
      nullptr, nullptr, nullptr, nullptr, nullptr);
  // G2: lp_f32 += L @ Wl  (M=50, split-K 4)
  gemmC<3><<<dim3(12, 1, 4), 256, 0, stream>>>(
      LC, 64, 50, WlC, H2, HH / 4, nullptr, lp_f32, H2, nullptr,
      nullptr, nullptr, nullptr, nullptr, nullptr);
  k_lp_finish<<<(nLP + 255) / 256, 256, 0, stream>>>(lp_f32, bl, LP, nLP);
  // G4: al += la @ W1l  (M=50, split-K 4); A = LP chunks 0..95
  gemmC<3><<<dim3(24, 1, 4), 256, 0, stream>>>(
      LP, 64, 50, W1C + (size_t)96 * H4 * 8, H4, HH / 4, nullptr, al, H4, nullptr,
      nullptr, nullptr, nullptr, nullptr, nullptr);
  // X chunked
  k_make_x<<<dim3(192, 50), 256, 0, stream>>>(TP, LP, XC);
  // G3: base = ta @ W1t (f32 row-major); A = TP chunks 0..95
  gemmC<1><<<dim3(24, 8), 256, 0, stream>>>(
      TP, 1024, 1024, W1C, H4, HH, nullptr, base, H4, nullptr,
      nullptr, nullptr, nullptr, nullptr, nullptr);

  k_init_out<<<(out_size + 255) / 256, 256, 0, stream>>>(out, b2, out_size);

  // G5: scorer, grid (24 n, 200 m = 50 bc x 4 s-tiles), n fastest
  gemmC<2><<<dim3(24, 200), 256, 0, stream>>>(
      XC, 512, 512, W1C + (size_t)192 * H4 * 8, H4, HH, nullptr, nullptr, 0,
      nullptr, base, al, b1, W2, out);
}